// Round 1
// baseline (442.153 us; speedup 1.0000x reference)
//
#include <hip/hip_runtime.h>
#include <cstdint>
#include <cstddef>

#define TOKENS 16384
#define DMODEL 4096
#define NEXP   64
#define TM     64
#define BK     64
#define NSPLIT 2
#define KSPAN  (DMODEL / NSPLIT)   // 2048
#define NSTEP  (KSPAN / BK)        // 32

// async global->LDS, 16B per lane (dst must be wave-uniform base + lane*16)
__device__ __forceinline__ void gld_lds16(const float* g, float* l) {
  __builtin_amdgcn_global_load_lds(
      (__attribute__((address_space(1))) const void*)g,
      (__attribute__((address_space(3))) void*)l,
      16, 0, 0);
}

// ---------------- kernel 1: W[e][d] -> Wt[d][e] (k-major) ----------------
__global__ __launch_bounds__(256)
void transpose_W(const float* __restrict__ W, float* __restrict__ Wt) {
  __shared__ float tile[64][65];
  const int tid = threadIdx.x;
  const int d0 = blockIdx.x * 64;
#pragma unroll
  for (int p = 0; p < 16; ++p) {
    int c = p * 256 + tid;
    int dl = c & 63, e = c >> 6;               // lanes: dl consecutive -> coalesced
    tile[e][dl] = W[(size_t)e * DMODEL + d0 + dl];
  }
  __syncthreads();
#pragma unroll
  for (int p = 0; p < 16; ++p) {
    int c = p * 256 + tid;
    int e = c & 63, dl = c >> 6;               // lanes: e consecutive -> coalesced
    Wt[(size_t)(d0 + dl) * NEXP + e] = tile[e][dl];
  }
}

// ---------------- kernel 2: partial logits GEMM ----------------
// grid (TOKENS/TM, NSPLIT), block 256. part[half][token][expert]
__global__ __launch_bounds__(256, 2)
void gemm_partial(const float* __restrict__ x, const float* __restrict__ Wt,
                  float* __restrict__ part) {
  __shared__ float xs[TM][BK + 4];   // +4 pad: row stride 272B (16B-aligned, bank-rotated)
  __shared__ float wsm[BK][NEXP];    // k-major: rows contiguous in experts

  const int tid = threadIdx.x;
  const int tx = tid & 15;           // expert group (4 experts)
  const int ty = tid >> 4;           // token group (4 tokens)
  const int t0 = blockIdx.x * TM;
  const int kbase = blockIdx.y * KSPAN;

  float acc[4][4];
#pragma unroll
  for (int i = 0; i < 4; ++i)
#pragma unroll
    for (int j = 0; j < 4; ++j) acc[i][j] = 0.f;

  float4 xreg[4];
  // prefetch x tile for step 0
#pragma unroll
  for (int p = 0; p < 4; ++p) {
    int c = p * 256 + tid;
    int cc = c & 15, tk = c >> 4;
    xreg[p] = *(const float4*)&x[(size_t)(t0 + tk) * DMODEL + kbase + cc * 4];
  }

  for (int s = 0; s < NSTEP; ++s) {
    __syncthreads();                 // previous tile's readers done
    // x regs -> LDS (conflict-free: bank = 4*(tk+cc) mod 32, uniform spread)
#pragma unroll
    for (int p = 0; p < 4; ++p) {
      int c = p * 256 + tid;
      int cc = c & 15, tk = c >> 4;
      *(float4*)&xs[tk][cc * 4] = xreg[p];
    }
    // W tile: contiguous 16KB of Wt, direct async global->LDS
    const float* wt = Wt + (size_t)(kbase + s * BK) * NEXP;
#pragma unroll
    for (int p = 0; p < 4; ++p) {
      int off = (p * 256 + tid) * 4;
      gld_lds16(wt + off, &wsm[0][0] + off);
    }
    __syncthreads();                 // drains glds (vmcnt) + ds_writes
    // issue next x prefetch now: its drain lands at next iteration's barrier (~2k cyc away)
    if (s + 1 < NSTEP) {
      const int k0n = kbase + (s + 1) * BK;
#pragma unroll
      for (int p = 0; p < 4; ++p) {
        int c = p * 256 + tid;
        int cc = c & 15, tk = c >> 4;
        xreg[p] = *(const float4*)&x[(size_t)(t0 + tk) * DMODEL + k0n + cc * 4];
      }
    }
    // compute: per k4: 4 x-reads (2-way, free) + 4 W-reads (contig, free) + 64 FMA
#pragma unroll
    for (int kk = 0; kk < BK; kk += 4) {
      float4 a[4], w[4];
#pragma unroll
      for (int i = 0; i < 4; ++i) a[i] = *(const float4*)&xs[ty * 4 + i][kk];
#pragma unroll
      for (int r = 0; r < 4; ++r) w[r] = *(const float4*)&wsm[kk + r][tx * 4];
#pragma unroll
      for (int r = 0; r < 4; ++r)
#pragma unroll
        for (int i = 0; i < 4; ++i) {
          float av = ((const float*)&a[i])[r];
#pragma unroll
          for (int j = 0; j < 4; ++j)
            acc[i][j] += av * ((const float*)&w[r])[j];
        }
    }
  }

  float* pbase = part + (size_t)blockIdx.y * TOKENS * NEXP;
#pragma unroll
  for (int i = 0; i < 4; ++i) {
    float4 v = make_float4(acc[i][0], acc[i][1], acc[i][2], acc[i][3]);
    *(float4*)&pbase[(size_t)(t0 + ty * 4 + i) * NEXP + tx * 4] = v;
  }
}

// ---------------- kernel 3: reduce halves + bias, top-2, softmax ----------------
// one wave per token; out = [indices as float (2*TOKENS)] ++ [scores (2*TOKENS)]
__global__ __launch_bounds__(256)
void topk_softmax(const float* __restrict__ part, const float* __restrict__ b,
                  float* __restrict__ out) {
  const int tid = threadIdx.x;
  const int lane = tid & 63;
  const int wv = tid >> 6;
  const int t = blockIdx.x * 4 + wv;

  float v = part[(size_t)t * NEXP + lane]
          + part[(size_t)(TOKENS + t) * NEXP + lane]
          + b[lane];

  // top-1 with lower-index tie-break (matches lax.top_k)
  float m1 = v; int i1 = lane;
#pragma unroll
  for (int off = 32; off > 0; off >>= 1) {
    float ov = __shfl_xor(m1, off, 64);
    int   oi = __shfl_xor(i1, off, 64);
    if (ov > m1 || (ov == m1 && oi < i1)) { m1 = ov; i1 = oi; }
  }
  // top-2
  float v2 = (lane == i1) ? -__builtin_inff() : v;
  float m2 = v2; int i2 = lane;
#pragma unroll
  for (int off = 32; off > 0; off >>= 1) {
    float ov = __shfl_xor(m2, off, 64);
    int   oi = __shfl_xor(i2, off, 64);
    if (ov > m2 || (ov == m2 && oi < i2)) { m2 = ov; i2 = oi; }
  }
  // softmax denominator: sum exp(v - max); max == m1
  float e = __expf(v - m1);
#pragma unroll
  for (int off = 32; off > 0; off >>= 1) e += __shfl_xor(e, off, 64);

  if (lane == 0) {
    out[(size_t)t * 2 + 0] = (float)i1;
    out[(size_t)t * 2 + 1] = (float)i2;
    float inv = 1.0f / e;
    out[(size_t)TOKENS * 2 + (size_t)t * 2 + 0] = inv;                   // exp(m1-m1)/sum
    out[(size_t)TOKENS * 2 + (size_t)t * 2 + 1] = __expf(m2 - m1) * inv; // exp(m2-m1)/sum
  }
}

extern "C" void kernel_launch(void* const* d_in, const int* in_sizes, int n_in,
                              void* d_out, int out_size, void* d_ws, size_t ws_size,
                              hipStream_t stream) {
  const float* x = (const float*)d_in[0];
  const float* W = (const float*)d_in[1];
  const float* b = (const float*)d_in[2];
  float* out = (float*)d_out;

  float* Wt   = (float*)d_ws;                      // 4096*64 floats = 1 MB
  float* part = Wt + (size_t)DMODEL * NEXP;        // 2*16384*64 floats = 8 MB

  hipLaunchKernelGGL(transpose_W, dim3(DMODEL / 64), dim3(256), 0, stream, W, Wt);
  hipLaunchKernelGGL(gemm_partial, dim3(TOKENS / TM, NSPLIT), dim3(256), 0, stream,
                     x, Wt, part);
  hipLaunchKernelGGL(topk_softmax, dim3(TOKENS / 4), dim3(256), 0, stream,
                     part, b, out);
}